// Round 13
// baseline (151.723 us; speedup 1.0000x reference)
//
#include <hip/hip_runtime.h>

#define LL 8
#define NN 100000
#define HH 128
#define KT 1024
#define BM 32
#define NNHH (NN * HH)
#define TILES 3125
#define PGRID 512

typedef __attribute__((ext_vector_type(4))) float f32x4;
typedef __attribute__((ext_vector_type(8))) short bf16x8;
typedef __attribute__((ext_vector_type(8))) unsigned short u16x8;

__device__ __forceinline__ unsigned short f2bf(float f) {
    unsigned u = __float_as_uint(f);
    unsigned r = ((u >> 16) & 1u) + 0x7fffu;   // RNE
    return (unsigned short)((u + r) >> 16);
}
__device__ __forceinline__ float bf2f(unsigned short s) {
    return __uint_as_float(((unsigned)s) << 16);
}
__device__ __forceinline__ f32x4 ntload4(const float* p) {
    return __builtin_nontemporal_load(reinterpret_cast<const f32x4*>(p));
}

// Pre-pack w_ref -> bf16 fragment order; also (re)init the tile counter to
// PGRID each launch (first PGRID tiles are implicitly blockIdx-assigned).
__global__ __launch_bounds__(256) void pack_w_kernel(const float* __restrict__ w_ref,
                                                     unsigned short* __restrict__ wp,
                                                     unsigned* __restrict__ ctr) {
    if (blockIdx.x == 0 && threadIdx.x == 0) *ctr = PGRID;
    int gid = blockIdx.x * 256 + threadIdx.x;   // 0..16383
    int col = gid >> 7;
    int k8  = gid & 127;
    const float* s = w_ref + (size_t)col * KT + (size_t)k8 * 8;
    float4 v0 = *reinterpret_cast<const float4*>(s);
    float4 v1 = *reinterpret_cast<const float4*>(s + 4);
    u16x8 p;
    p[0] = f2bf(v0.x); p[1] = f2bf(v0.y); p[2] = f2bf(v0.z); p[3] = f2bf(v0.w);
    p[4] = f2bf(v1.x); p[5] = f2bf(v1.y); p[6] = f2bf(v1.z); p[7] = f2bf(v1.w);
    *reinterpret_cast<u16x8*>(wp + (size_t)(k8 * 128 + col) * 8) = p;
}

// PERSISTENT kernel: 512 blocks (2/CU), 512 threads = 8 waves; dynamic tile
// queue (global atomic). Per tile (32 nodes): r9/r10 interleaved pipeline with
// lgkm-only barriers; pf depth-4 keyed by L&3 (L3 at step0, L4..7 at steps
// 1..4, NEXT tile's L0..2 at steps 5..7 -> pipeline primed across tiles; the
// epilogue runs while next tile's HBM loads are in flight). B depth-2 rolling.
// All 8 layers LDS-resident per tile; xs read from HBM exactly ONCE.
__global__ __launch_bounds__(512, 2)
void gamlp_persist(const float* __restrict__ xs,
                   const unsigned short* __restrict__ wp,
                   const float* __restrict__ b_ref,
                   const float* __restrict__ w_att,
                   const float* __restrict__ b_att_p,
                   const float* __restrict__ alpha_p,
                   float* __restrict__ out,
                   unsigned* __restrict__ ctr)
{
    __shared__ unsigned short A_lds[LL][BM * 128];  // 64KB, XOR-swizzled slots
    __shared__ float sjk_lds[BM][8];
    __shared__ unsigned s_next;

    const int tid  = threadIdx.x;
    const int lane = tid & 63;
    const int wave = tid >> 6;      // 0..7
    const int colq = lane & 15;
    const int kq   = lane >> 4;

    const float alpha = *alpha_p;
    const float batt  = *b_att_p;

    const int slot = tid & 15;
    const int row  = tid >> 4;          // 0..31
    const int thr_off = row * HH + slot * 8;
    const int doff = row * 128 + ((slot ^ (row & 15)) * 8);

    const f32x4 wax0 = *reinterpret_cast<const f32x4*>(w_att + HH + slot * 8);
    const f32x4 wax1 = *reinterpret_cast<const f32x4*>(w_att + HH + slot * 8 + 4);

    const unsigned short* pB = wp + (size_t)(wave * 16 + colq) * 8;
    const float wr = w_att[wave * 16 + colq];
    const float br = b_ref[wave * 16 + colq];

    f32x4 pf[4][2];
    bf16x8 BA[4], BB[4];

#define ISSUE_B(DST, K8STEP) do {                                                \
    const int k8_ = (K8STEP) * 16;                                               \
    _Pragma("unroll")                                                            \
    for (int c_ = 0; c_ < 4; c_++)                                               \
        DST[c_] = *reinterpret_cast<const bf16x8*>(                              \
            pB + (size_t)(k8_ + c_ * 4 + kq) * 1024);                            \
} while (0)

#define LOADS(SET, BASE, L) do {                                                 \
    const float* p_ = (BASE) + (size_t)(L) * NNHH;                               \
    pf[SET][0] = ntload4(p_);                                                    \
    pf[SET][1] = ntload4(p_ + 4);                                                \
} while (0)

#define CONVERT_WRITE(SET, L) do {                                               \
    u16x8 pk_;                                                                   \
    _Pragma("unroll")                                                            \
    for (int e_ = 0; e_ < 4; e_++) {                                             \
        pk_[e_]   = f2bf(pf[SET][0][e_]);                                        \
        pk_[e_+4] = f2bf(pf[SET][1][e_]);                                        \
    }                                                                            \
    *reinterpret_cast<u16x8*>(&A_lds[L][doff]) = pk_;                            \
} while (0)

#define LGKM_BARRIER() do {                                                      \
    asm volatile("s_waitcnt lgkmcnt(0)" ::: "memory");                           \
    __builtin_amdgcn_s_barrier();                                                \
} while (0)

    // ---- first tile: implicit assignment = blockIdx ----
    int n0 = blockIdx.x * BM;
    const float* srcT = xs + (size_t)n0 * HH - n0 * 0 + thr_off;
    srcT = xs + (size_t)n0 * HH + thr_off;

    ISSUE_B(BA, 0);
    ISSUE_B(BB, 1);
    LOADS(0, srcT, 0);
    LOADS(1, srcT, 1);
    LOADS(2, srcT, 2);
    CONVERT_WRITE(0, 0);
    LGKM_BARRIER();

    while (true) {
        f32x4 acc[2];
        acc[0] = (f32x4){0, 0, 0, 0};
        acc[1] = (f32x4){0, 0, 0, 0};

        int tile_next = 0;
        bool have_next = false;
        const float* srcN = srcT;

        #pragma unroll
        for (int s = 0; s < 8; s++) {
            if (s == 0) {
                if (tid == 0) s_next = atomicAdd(ctr, 1u);
            }
            if (s == 5) {
                tile_next = (int)s_next;           // written at s=0, 5 barriers ago
                have_next = (tile_next < TILES);
                srcN = xs + (size_t)tile_next * BM * HH + thr_off;
            }
            // A loads: current tile L3..7 at steps 0..4; next tile L0..2 at 5..7
            if (s <= 4) {
                LOADS((s + 3) & 3, srcT, s + 3);
            } else if (have_next) {
                LOADS(s - 5, srcN, s - 5);
            }
            // convert + ds_write layer s+1 (loaded >=2 steps ago)
            if (s <= 6) CONVERT_WRITE((s + 1) & 3, s + 1);
            // MFMA on layer s's resident tile with BA = B(s)
            #pragma unroll
            for (int c = 0; c < 4; c++) {
                bf16x8 af[2];
                #pragma unroll
                for (int m = 0; m < 2; m++) {
                    int r = m * 16 + colq;
                    af[m] = *reinterpret_cast<const bf16x8*>(
                        &A_lds[s][r * 128 + (((c * 4 + kq) ^ colq) * 8)]);
                }
                acc[0] = __builtin_amdgcn_mfma_f32_16x16x32_bf16(af[0], BA[c], acc[0], 0, 0, 0);
                acc[1] = __builtin_amdgcn_mfma_f32_16x16x32_bf16(af[1], BA[c], acc[1], 0, 0, 0);
            }
            // roll B pipeline: BA <- BB, issue B((s+2)&7) into BB
            #pragma unroll
            for (int c = 0; c < 4; c++) BA[c] = BB[c];
            ISSUE_B(BB, (s + 2) & 7);
            LGKM_BARRIER();
        }

        // ---- sjk: sum over this wave's 16 cols of prelu(jk + b_ref) * wa_ref ----
        #pragma unroll
        for (int m = 0; m < 2; m++) {
            float sr[4];
            #pragma unroll
            for (int r = 0; r < 4; r++) {
                float v = acc[m][r] + br;
                v = (v >= 0.f) ? v : alpha * v;
                float sv = v * wr;
                sv += __shfl_xor(sv, 1);
                sv += __shfl_xor(sv, 2);
                sv += __shfl_xor(sv, 4);
                sv += __shfl_xor(sv, 8);
                sr[r] = sv;
            }
            if (colq == 0) {
                #pragma unroll
                for (int r = 0; r < 4; r++)
                    sjk_lds[m * 16 + kq * 4 + r][wave] = sr[r];
            }
        }
        LGKM_BARRIER();

        // ---- epilogue (overlaps next tile's in-flight HBM loads) ----
        {
            float sx[LL];
            #pragma unroll
            for (int l = 0; l < LL; l++) {
                u16x8 v = *reinterpret_cast<const u16x8*>(&A_lds[l][doff]);
                float d = 0.f;
                #pragma unroll
                for (int e = 0; e < 4; e++)
                    d += bf2f(v[e]) * wax0[e] + bf2f(v[e + 4]) * wax1[e];
                sx[l] = d;
            }
            #pragma unroll
            for (int mser = 1; mser <= 8; mser <<= 1) {
                #pragma unroll
                for (int l = 0; l < LL; l++) sx[l] += __shfl_xor(sx[l], mser);
            }
            float sjk = 0.f;
            #pragma unroll
            for (int w8 = 0; w8 < 8; w8++) sjk += sjk_lds[row][w8];
            float sc[LL], mx = 0.f;
            #pragma unroll
            for (int l = 0; l < LL; l++) {
                float sv = fmaxf(sjk + sx[l] + batt, 0.f);
                sc[l] = sv;
                mx = fmaxf(mx, sv);
            }
            float den = 0.f;
            #pragma unroll
            for (int l = 0; l < LL; l++) { sc[l] = __expf(sc[l] - mx); den += sc[l]; }
            float inv = 1.f / den;
            f32x4 o0 = (f32x4){0, 0, 0, 0};
            f32x4 o1 = (f32x4){0, 0, 0, 0};
            #pragma unroll
            for (int l = 0; l < LL; l++) {
                u16x8 v = *reinterpret_cast<const u16x8*>(&A_lds[l][doff]);
                float wl = sc[l] * inv;
                #pragma unroll
                for (int e = 0; e < 4; e++) {
                    o0[e] += wl * bf2f(v[e]);
                    o1[e] += wl * bf2f(v[e + 4]);
                }
            }
            float* op = out + (size_t)n0 * HH + thr_off;
            __builtin_nontemporal_store(o0, reinterpret_cast<f32x4*>(op));
            __builtin_nontemporal_store(o1, reinterpret_cast<f32x4*>(op + 4));
        }
        LGKM_BARRIER();   // A_lds reads complete before next tile's L0 convert

        if (!have_next) break;
        CONVERT_WRITE(0, 0);     // next tile's layer 0 (set 0, loaded at step 5)
        LGKM_BARRIER();
        n0 = tile_next * BM;
        srcT = srcN;
    }
#undef ISSUE_B
#undef LOADS
#undef CONVERT_WRITE
#undef LGKM_BARRIER
}

extern "C" void kernel_launch(void* const* d_in, const int* in_sizes, int n_in,
                              void* d_out, int out_size, void* d_ws, size_t ws_size,
                              hipStream_t stream) {
    const float* xs     = (const float*)d_in[0];
    const float* w_ref  = (const float*)d_in[1];
    const float* b_ref  = (const float*)d_in[2];
    const float* w_att  = (const float*)d_in[3];
    const float* b_att  = (const float*)d_in[4];
    const float* alpha  = (const float*)d_in[5];
    float* out = (float*)d_out;
    unsigned short* wp = (unsigned short*)d_ws;             // 256 KB packed bf16 weights
    unsigned* ctr = (unsigned*)((char*)d_ws + 262144);      // tile counter

    pack_w_kernel<<<64, 256, 0, stream>>>(w_ref, wp, ctr);
    gamlp_persist<<<PGRID, 512, 0, stream>>>(xs, wp, b_ref, w_att, b_att, alpha, out, ctr);
}

// Round 14
// 149.200 us; speedup vs baseline: 1.0169x; 1.0169x over previous
//
#include <hip/hip_runtime.h>

#define LL 8
#define NN 100000
#define HH 128
#define KT 1024
#define BM 16
#define NNHH (NN * HH)

typedef __attribute__((ext_vector_type(4))) float f32x4;
typedef __attribute__((ext_vector_type(8))) short bf16x8;
typedef __attribute__((ext_vector_type(8))) unsigned short u16x8;

__device__ __forceinline__ unsigned short f2bf(float f) {
    unsigned u = __float_as_uint(f);
    unsigned r = ((u >> 16) & 1u) + 0x7fffu;   // RNE
    return (unsigned short)((u + r) >> 16);
}
__device__ __forceinline__ float bf2f(unsigned short s) {
    return __uint_as_float(((unsigned)s) << 16);
}
__device__ __forceinline__ f32x4 ntload4(const float* p) {
    return __builtin_nontemporal_load(reinterpret_cast<const f32x4*>(p));
}

// Pre-pack w_ref (f32 [128 cols][1024 k]) -> bf16 in fragment order:
// wp[(k8*128 + col)*8 + e] = bf16(w_ref[col][k8*8+e]),  k8 = k/8.
__global__ __launch_bounds__(256) void pack_w_kernel(const float* __restrict__ w_ref,
                                                     unsigned short* __restrict__ wp) {
    int gid = blockIdx.x * 256 + threadIdx.x;   // 0..16383
    int col = gid >> 7;
    int k8  = gid & 127;
    const float* s = w_ref + (size_t)col * KT + (size_t)k8 * 8;
    float4 v0 = *reinterpret_cast<const float4*>(s);
    float4 v1 = *reinterpret_cast<const float4*>(s + 4);
    u16x8 p;
    p[0] = f2bf(v0.x); p[1] = f2bf(v0.y); p[2] = f2bf(v0.z); p[3] = f2bf(v0.w);
    p[4] = f2bf(v1.x); p[5] = f2bf(v1.y); p[6] = f2bf(v1.z); p[7] = f2bf(v1.w);
    *reinterpret_cast<u16x8*>(wp + (size_t)(k8 * 128 + col) * 8) = p;
}

// Block = 16 nodes (6250 blocks exact), 256 threads = 4 waves, ~32.3KB LDS ->
// FOUR blocks/CU = 4 independent barrier domains (16 waves/CU). Wave w: 16
// nodes x cols [w*32,+32). r9 pipeline: A depth-3 register prefetch, lgkm-only
// barriers (loads in flight across s_barrier), NT loads/stores, 8 layer-
// resident bf16 LDS tiles, epilogue sx+softmax+weighted-sum from LDS.
// B: single register set, issued for step s+1 right after step s's MFMAs
// (full step + barrier of L2 latency cover). xs read from HBM exactly ONCE.
__global__ __launch_bounds__(256, 4)
void gamlp_main(const float* __restrict__ xs,
                const unsigned short* __restrict__ wp,
                const float* __restrict__ b_ref,
                const float* __restrict__ w_att,
                const float* __restrict__ b_att_p,
                const float* __restrict__ alpha_p,
                float* __restrict__ out)
{
    __shared__ unsigned short A_lds[LL][BM * 128];  // 8 x 4KB = 32KB, XOR-swizzled slots
    __shared__ float sjk_lds[BM][4];

    const int tid  = threadIdx.x;
    const int lane = tid & 63;
    const int wave = tid >> 6;      // 0..3
    const int colq = lane & 15;
    const int kq   = lane >> 4;
    const int n0   = blockIdx.x * BM;

    const float alpha = *alpha_p;
    const float batt  = *b_att_p;

    // ---- staging map: thread covers (row = tid>>4 in 0..15, 16B slot = tid&15) ----
    const int slot = tid & 15;
    const int row  = tid >> 4;
    const float* src = xs + (size_t)(n0 + row) * HH + slot * 8;
    const int doff = row * 128 + ((slot ^ row) * 8);

    // wa_x slice for this thread's k-slot (f32)
    const f32x4 wax0 = *reinterpret_cast<const f32x4*>(w_att + HH + slot * 8);
    const f32x4 wax1 = *reinterpret_cast<const f32x4*>(w_att + HH + slot * 8 + 4);

    // ---- B fragment pointers (packed bf16, L2-resident); wave covers 32 cols ----
    const unsigned short* pB0 = wp + (size_t)(wave * 32 + colq) * 8;
    const unsigned short* pB1 = pB0 + 128;      // +16 cols

    const float wr0 = w_att[wave * 32 + colq],  wr1 = w_att[wave * 32 + 16 + colq];
    const float br0 = b_ref[wave * 32 + colq],  br1 = b_ref[wave * 32 + 16 + colq];

    f32x4 acc[2];
    acc[0] = (f32x4){0, 0, 0, 0};
    acc[1] = (f32x4){0, 0, 0, 0};

    f32x4 pf[3][2];
    bf16x8 BA[4][2];    // single B set: current step's 4 c-chunks x 2 col-groups

#define ISSUE_B(STEP) do {                                                       \
    const int k8_ = (STEP) * 16;                                                 \
    _Pragma("unroll")                                                            \
    for (int c_ = 0; c_ < 4; c_++) {                                             \
        BA[c_][0] = *reinterpret_cast<const bf16x8*>(                            \
            pB0 + (size_t)(k8_ + c_ * 4 + kq) * 1024);                           \
        BA[c_][1] = *reinterpret_cast<const bf16x8*>(                            \
            pB1 + (size_t)(k8_ + c_ * 4 + kq) * 1024);                           \
    }                                                                            \
} while (0)

#define LOADS(SET, LAY) do {                                                     \
    const size_t g_ = (size_t)(LAY) * NNHH;                                      \
    pf[SET][0] = ntload4(src + g_);                                              \
    pf[SET][1] = ntload4(src + g_ + 4);                                          \
} while (0)

// pure convert + LDS write (sx lives in the epilogue)
#define CONVERT_WRITE(SET, LAY) do {                                             \
    u16x8 pk_;                                                                   \
    _Pragma("unroll")                                                            \
    for (int e_ = 0; e_ < 4; e_++) {                                             \
        pk_[e_]   = f2bf(pf[SET][0][e_]);                                        \
        pk_[e_+4] = f2bf(pf[SET][1][e_]);                                        \
    }                                                                            \
    *reinterpret_cast<u16x8*>(&A_lds[LAY][doff]) = pk_;                          \
} while (0)

#define LGKM_BARRIER() do {                                                      \
    asm volatile("s_waitcnt lgkmcnt(0)" ::: "memory");                           \
    __builtin_amdgcn_s_barrier();                                                \
} while (0)

    // ---- prologue: B(0) first; 3 A-layers in flight; convert layer 0 ----
    ISSUE_B(0);
    LOADS(0, 0);
    LOADS(1, 1);
    LOADS(2, 2);
    CONVERT_WRITE(0, 0);
    LGKM_BARRIER();

    // ---- main loop: 8 steps (step == layer), fully unrolled ----
    #pragma unroll
    for (int s = 0; s < 8; s++) {
        // (1) A loads: depth-3 register pipeline
        if (s + 3 < 8) LOADS((s + 3) % 3, s + 3);
        // (2) convert + ds_write layer s+1 (its loads issued 2 steps ago)
        if (s + 1 < 8) CONVERT_WRITE((s + 1) % 3, s + 1);
        // (3) MFMA on layer s's resident tile with BA = B(s)
        #pragma unroll
        for (int c = 0; c < 4; c++) {
            bf16x8 af = *reinterpret_cast<const bf16x8*>(
                &A_lds[s][colq * 128 + (((c * 4 + kq) ^ colq) * 8)]);
            acc[0] = __builtin_amdgcn_mfma_f32_16x16x32_bf16(af, BA[c][0], acc[0], 0, 0, 0);
            acc[1] = __builtin_amdgcn_mfma_f32_16x16x32_bf16(af, BA[c][1], acc[1], 0, 0, 0);
        }
        // (4) issue B(s+1): a whole step + barrier of latency cover, 1 set live
        if (s < 7) ISSUE_B(s + 1);
        LGKM_BARRIER();
    }

    // ---- sjk: sum over this wave's 32 cols of prelu(jk + b_ref) * wa_ref ----
    // D layout: col = wave*32 + n*16 + colq, node = kq*4 + r
    {
        float sr[4];
        #pragma unroll
        for (int r = 0; r < 4; r++) {
            float v0 = acc[0][r] + br0;  v0 = (v0 >= 0.f) ? v0 : alpha * v0;
            float v1 = acc[1][r] + br1;  v1 = (v1 >= 0.f) ? v1 : alpha * v1;
            float sv = v0 * wr0 + v1 * wr1;
            sv += __shfl_xor(sv, 1);
            sv += __shfl_xor(sv, 2);
            sv += __shfl_xor(sv, 4);
            sv += __shfl_xor(sv, 8);
            sr[r] = sv;
        }
        if (colq == 0) {
            #pragma unroll
            for (int r = 0; r < 4; r++)
                sjk_lds[kq * 4 + r][wave] = sr[r];
        }
    }
    __syncthreads();

    // ---- epilogue: sx from LDS bf16 tiles (batched butterfly), softmax,
    //      weighted sum. Thread handles (node = row, slot); xs NOT re-read. ----
    {
        const int node = row;
        // pass 1: per-layer partial dots (independent -> ILP)
        float sx[LL];
        #pragma unroll
        for (int l = 0; l < LL; l++) {
            u16x8 v = *reinterpret_cast<const u16x8*>(&A_lds[l][doff]);
            float d = 0.f;
            #pragma unroll
            for (int e = 0; e < 4; e++)
                d += bf2f(v[e]) * wax0[e] + bf2f(v[e + 4]) * wax1[e];
            sx[l] = d;
        }
        // batched butterfly over the 16-slot group: 4 levels x 8 layers, ILP 8
        #pragma unroll
        for (int mser = 1; mser <= 8; mser <<= 1) {
            #pragma unroll
            for (int l = 0; l < LL; l++) sx[l] += __shfl_xor(sx[l], mser);
        }
        float sjk = sjk_lds[node][0] + sjk_lds[node][1] + sjk_lds[node][2] + sjk_lds[node][3];
        float sc[LL], mx = 0.f;
        #pragma unroll
        for (int l = 0; l < LL; l++) {
            float sv = fmaxf(sjk + sx[l] + batt, 0.f);
            sc[l] = sv;
            mx = fmaxf(mx, sv);
        }
        float den = 0.f;
        #pragma unroll
        for (int l = 0; l < LL; l++) { sc[l] = __expf(sc[l] - mx); den += sc[l]; }
        float inv = 1.f / den;
        f32x4 o0 = (f32x4){0, 0, 0, 0};
        f32x4 o1 = (f32x4){0, 0, 0, 0};
        #pragma unroll
        for (int l = 0; l < LL; l++) {
            u16x8 v = *reinterpret_cast<const u16x8*>(&A_lds[l][doff]);
            float wl = sc[l] * inv;
            #pragma unroll
            for (int e = 0; e < 4; e++) {
                o0[e] += wl * bf2f(v[e]);
                o1[e] += wl * bf2f(v[e + 4]);
            }
        }
        float* op = out + (size_t)(n0 + node) * HH + slot * 8;
        __builtin_nontemporal_store(o0, reinterpret_cast<f32x4*>(op));
        __builtin_nontemporal_store(o1, reinterpret_cast<f32x4*>(op + 4));
    }
#undef ISSUE_B
#undef LOADS
#undef CONVERT_WRITE
#undef LGKM_BARRIER
}

extern "C" void kernel_launch(void* const* d_in, const int* in_sizes, int n_in,
                              void* d_out, int out_size, void* d_ws, size_t ws_size,
                              hipStream_t stream) {
    const float* xs     = (const float*)d_in[0];
    const float* w_ref  = (const float*)d_in[1];
    const float* b_ref  = (const float*)d_in[2];
    const float* w_att  = (const float*)d_in[3];
    const float* b_att  = (const float*)d_in[4];
    const float* alpha  = (const float*)d_in[5];
    float* out = (float*)d_out;
    unsigned short* wp = (unsigned short*)d_ws;   // 256 KB packed bf16 weights

    pack_w_kernel<<<64, 256, 0, stream>>>(w_ref, wp);
    const int grid = NN / BM;                     // 6250, exact
    gamlp_main<<<grid, 256, 0, stream>>>(xs, wp, b_ref, w_att, b_att, alpha, out);
}

// Round 15
// 125.529 us; speedup vs baseline: 1.2087x; 1.1886x over previous
//
#include <hip/hip_runtime.h>
#include <hip/hip_bf16.h>

#define LL 8
#define NN 100000
#define HH 128
#define KT 1024
#define BM 32
#define NNHH (NN * HH)

typedef __attribute__((ext_vector_type(4))) float f32x4;
typedef __attribute__((ext_vector_type(8))) short bf16x8;
typedef __attribute__((ext_vector_type(8))) unsigned short u16x8;

// native conversion: compiler emits v_cvt_pk_bf16_f32 for adjacent pairs (m240:
// scalar-cast path beats hand-rolled bit-twiddle; do NOT hand-roll RNE)
__device__ __forceinline__ unsigned short f2bf(float f) {
    __hip_bfloat16 h = __float2bfloat16(f);
    return *reinterpret_cast<unsigned short*>(&h);
}
__device__ __forceinline__ float bf2f(unsigned short s) {
    return __uint_as_float(((unsigned)s) << 16);
}
__device__ __forceinline__ f32x4 ntload4(const float* p) {
    return __builtin_nontemporal_load(reinterpret_cast<const f32x4*>(p));
}

// Pre-pack w_ref (f32 [128 cols][1024 k]) -> bf16 in fragment order:
// wp[(k8*128 + col)*8 + e] = bf16(w_ref[col][k8*8+e]),  k8 = k/8.
__global__ __launch_bounds__(256) void pack_w_kernel(const float* __restrict__ w_ref,
                                                     unsigned short* __restrict__ wp) {
    int gid = blockIdx.x * 256 + threadIdx.x;   // 0..16383
    int col = gid >> 7;
    int k8  = gid & 127;
    const float* s = w_ref + (size_t)col * KT + (size_t)k8 * 8;
    float4 v0 = *reinterpret_cast<const float4*>(s);
    float4 v1 = *reinterpret_cast<const float4*>(s + 4);
    u16x8 p;
    p[0] = f2bf(v0.x); p[1] = f2bf(v0.y); p[2] = f2bf(v0.z); p[3] = f2bf(v0.w);
    p[4] = f2bf(v1.x); p[5] = f2bf(v1.y); p[6] = f2bf(v1.z); p[7] = f2bf(v1.w);
    *reinterpret_cast<u16x8*>(wp + (size_t)(k8 * 128 + col) * 8) = p;
}

// r9 champion structure: block = 32 nodes (3125 exact), 512 threads = 8 waves
// (2 blocks/CU = 16 waves/CU); wave w: 32 nodes x cols [w*16,+16). Interleaved
// per-layer pipeline: A depth-3 register prefetch, B register double-buffer,
// lgkm-only barriers (HBM loads stay in flight across s_barrier), NT loads/
// stores, 8 layer-resident bf16 LDS tiles, epilogue (sx batched butterfly +
// softmax + weighted sum) fed from LDS. xs read from HBM exactly ONCE.
// Round-15 delta: native __float2bfloat16 converts (v_cvt_pk-fusable), no
// trailing barrier after the last MFMA step.
__global__ __launch_bounds__(512, 2)
void gamlp_main(const float* __restrict__ xs,
                const unsigned short* __restrict__ wp,
                const float* __restrict__ b_ref,
                const float* __restrict__ w_att,
                const float* __restrict__ b_att_p,
                const float* __restrict__ alpha_p,
                float* __restrict__ out)
{
    __shared__ unsigned short A_lds[LL][BM * 128];  // 8 x 8KB = 64KB, XOR-swizzled slots
    __shared__ float sjk_lds[BM][8];

    const int tid  = threadIdx.x;
    const int lane = tid & 63;
    const int wave = tid >> 6;      // 0..7
    const int colq = lane & 15;
    const int kq   = lane >> 4;
    const int n0   = blockIdx.x * BM;

    const float alpha = *alpha_p;
    const float batt  = *b_att_p;

    // ---- staging map: thread covers (row = tid>>4 in 0..31, 16B slot = tid&15) ----
    const int slot = tid & 15;
    const int row  = tid >> 4;
    const float* src = xs + (size_t)(n0 + row) * HH + slot * 8;
    const int doff = row * 128 + ((slot ^ (row & 15)) * 8);

    // wa_x slice for this thread's k-slot (f32)
    const f32x4 wax0 = *reinterpret_cast<const f32x4*>(w_att + HH + slot * 8);
    const f32x4 wax1 = *reinterpret_cast<const f32x4*>(w_att + HH + slot * 8 + 4);

    // ---- B fragment pointer (packed bf16, L2-resident); wave covers 16 cols ----
    const unsigned short* pB = wp + (size_t)(wave * 16 + colq) * 8;
    const float wr = w_att[wave * 16 + colq];
    const float br = b_ref[wave * 16 + colq];

    f32x4 acc[2];
    acc[0] = (f32x4){0, 0, 0, 0};
    acc[1] = (f32x4){0, 0, 0, 0};

    f32x4 pf[3][2];
    bf16x8 Bc[4], Bn[4];

#define LOADS(SET, LAY) do {                                                     \
    const size_t g_ = (size_t)(LAY) * NNHH;                                      \
    pf[SET][0] = ntload4(src + g_);                                              \
    pf[SET][1] = ntload4(src + g_ + 4);                                          \
} while (0)

// pure convert + LDS write (sx lives in the epilogue); native casts
#define CONVERT_WRITE(SET, LAY) do {                                             \
    u16x8 pk_;                                                                   \
    _Pragma("unroll")                                                            \
    for (int e_ = 0; e_ < 4; e_++) {                                             \
        pk_[e_]   = f2bf(pf[SET][0][e_]);                                        \
        pk_[e_+4] = f2bf(pf[SET][1][e_]);                                        \
    }                                                                            \
    *reinterpret_cast<u16x8*>(&A_lds[LAY][doff]) = pk_;                          \
} while (0)

#define LGKM_BARRIER() do {                                                      \
    asm volatile("s_waitcnt lgkmcnt(0)" ::: "memory");                           \
    __builtin_amdgcn_s_barrier();                                                \
} while (0)

    // ---- B double-buffer: preload step 0's 4 fragments ----
    #pragma unroll
    for (int c = 0; c < 4; c++)
        Bc[c] = *reinterpret_cast<const bf16x8*>(pB + (size_t)(c * 4 + kq) * 1024);

    // ---- prologue: 3 layers of loads in flight, convert layer 0 ----
    LOADS(0, 0);
    LOADS(1, 1);
    LOADS(2, 2);
    CONVERT_WRITE(0, 0);
    LGKM_BARRIER();

    // ---- main loop: 8 steps (step == layer), fully unrolled ----
    #pragma unroll
    for (int s = 0; s < 8; s++) {
        if (s + 3 < 8) LOADS((s + 3) % 3, s + 3);
        if (s + 1 < 8) CONVERT_WRITE((s + 1) % 3, s + 1);
        // prefetch next step's B fragments (in flight during MFMAs)
        if (s < 7) {
            const int k8n = (s + 1) * 16;
            #pragma unroll
            for (int c = 0; c < 4; c++)
                Bn[c] = *reinterpret_cast<const bf16x8*>(pB + (size_t)(k8n + c * 4 + kq) * 1024);
        }
        // MFMA on layer s's resident tile
        #pragma unroll
        for (int c = 0; c < 4; c++) {
            bf16x8 af[2];
            #pragma unroll
            for (int m = 0; m < 2; m++) {
                int r = m * 16 + colq;
                af[m] = *reinterpret_cast<const bf16x8*>(
                    &A_lds[s][r * 128 + (((c * 4 + kq) ^ colq) * 8)]);
            }
            acc[0] = __builtin_amdgcn_mfma_f32_16x16x32_bf16(af[0], Bc[c], acc[0], 0, 0, 0);
            acc[1] = __builtin_amdgcn_mfma_f32_16x16x32_bf16(af[1], Bc[c], acc[1], 0, 0, 0);
        }
        #pragma unroll
        for (int c = 0; c < 4; c++) Bc[c] = Bn[c];
        if (s < 7) LGKM_BARRIER();   // no barrier needed after the last MFMA step
    }

    // ---- sjk: sum over this wave's 16 cols of prelu(jk + b_ref) * wa_ref ----
    // D layout: col = wave*16 + colq, node = m*16 + kq*4 + r
    #pragma unroll
    for (int m = 0; m < 2; m++) {
        float sr[4];
        #pragma unroll
        for (int r = 0; r < 4; r++) {
            float v = acc[m][r] + br;
            v = (v >= 0.f) ? v : alpha * v;
            float sv = v * wr;
            sv += __shfl_xor(sv, 1);
            sv += __shfl_xor(sv, 2);
            sv += __shfl_xor(sv, 4);
            sv += __shfl_xor(sv, 8);
            sr[r] = sv;
        }
        if (colq == 0) {
            #pragma unroll
            for (int r = 0; r < 4; r++)
                sjk_lds[m * 16 + kq * 4 + r][wave] = sr[r];
        }
    }
    __syncthreads();

    // ---- epilogue: sx from LDS bf16 tiles (batched butterfly), softmax,
    //      weighted sum. Thread handles (node = row, slot); xs NOT re-read. ----
    {
        const int node = row;
        const int boff = node * 128 + ((slot ^ (node & 15)) * 8);
        // pass 1: per-layer partial dots (independent -> ILP)
        float sx[LL];
        #pragma unroll
        for (int l = 0; l < LL; l++) {
            u16x8 v = *reinterpret_cast<const u16x8*>(&A_lds[l][boff]);
            float d = 0.f;
            #pragma unroll
            for (int e = 0; e < 4; e++)
                d += bf2f(v[e]) * wax0[e] + bf2f(v[e + 4]) * wax1[e];
            sx[l] = d;
        }
        // batched butterfly over the 16-slot group: 4 levels x 8 layers, ILP 8
        #pragma unroll
        for (int mser = 1; mser <= 8; mser <<= 1) {
            #pragma unroll
            for (int l = 0; l < LL; l++) sx[l] += __shfl_xor(sx[l], mser);
        }
        float sjk = 0.f;
        #pragma unroll
        for (int w8 = 0; w8 < 8; w8++) sjk += sjk_lds[node][w8];
        float sc[LL], mx = 0.f;
        #pragma unroll
        for (int l = 0; l < LL; l++) {
            float sv = fmaxf(sjk + sx[l] + batt, 0.f);
            sc[l] = sv;
            mx = fmaxf(mx, sv);
        }
        float den = 0.f;
        #pragma unroll
        for (int l = 0; l < LL; l++) { sc[l] = __expf(sc[l] - mx); den += sc[l]; }
        float inv = 1.f / den;
        // pass 2: weighted sum
        f32x4 o0 = (f32x4){0.f, 0.f, 0.f, 0.f};
        f32x4 o1 = (f32x4){0.f, 0.f, 0.f, 0.f};
        #pragma unroll
        for (int l = 0; l < LL; l++) {
            u16x8 v = *reinterpret_cast<const u16x8*>(&A_lds[l][boff]);
            float wl = sc[l] * inv;
            #pragma unroll
            for (int e = 0; e < 4; e++) {
                o0[e] += wl * bf2f(v[e]);
                o1[e] += wl * bf2f(v[e + 4]);
            }
        }
        float* op = out + (size_t)(n0 + node) * HH + slot * 8;
        __builtin_nontemporal_store(o0, reinterpret_cast<f32x4*>(op));
        __builtin_nontemporal_store(o1, reinterpret_cast<f32x4*>(op + 4));
    }
#undef LOADS
#undef CONVERT_WRITE
#undef LGKM_BARRIER
}

extern "C" void kernel_launch(void* const* d_in, const int* in_sizes, int n_in,
                              void* d_out, int out_size, void* d_ws, size_t ws_size,
                              hipStream_t stream) {
    const float* xs     = (const float*)d_in[0];
    const float* w_ref  = (const float*)d_in[1];
    const float* b_ref  = (const float*)d_in[2];
    const float* w_att  = (const float*)d_in[3];
    const float* b_att  = (const float*)d_in[4];
    const float* alpha  = (const float*)d_in[5];
    float* out = (float*)d_out;
    unsigned short* wp = (unsigned short*)d_ws;   // 256 KB packed bf16 weights

    pack_w_kernel<<<64, 256, 0, stream>>>(w_ref, wp);
    const int grid = NN / BM;                     // 3125, exact
    gamlp_main<<<grid, 512, 0, stream>>>(xs, wp, b_ref, w_att, b_att, alpha, out);
}